// Round 5
// baseline (951.396 us; speedup 1.0000x reference)
//
#include <hip/hip_runtime.h>
#include <math.h>

// Problem constants
#define KCODES 1024
#define DIMV   64
#define NROWS  131072   // 32*64*64
#define HWSZ   4096     // 64*64
#define NELEM  8388608  // 32*64*64*64

// ws layout (bytes):
//   0      : double loss_sum          (8)
//   8      : int    counts[1024]      (4096)
//   4104   : float  dw[65536]         (262144)
//   266248 : float  s_w[1024]         (4096)    fp32 |w_k|^2, numpy pairwise order
//   270344 : float  WT[64*1024]       (262144)  transposed codebook WT[i][k]
//   532488 : double adjd[1024]        (8192)    fp64 adjusted cluster size
// zeroed region = first 266248 bytes

// ---- prep: s_w in numpy scalar-pairwise order (identical to passing r2/r3 code) ----
__global__ __launch_bounds__(256) void vq_prep_kernel(
    const float* __restrict__ emb, float* __restrict__ s_w)
{
    int k = blockIdx.x * 256 + threadIdx.x;   // grid 4*256 = 1024 codes
    const float* v = emb + k * DIMV;
    float r[8];
    #pragma unroll
    for (int j = 0; j < 8; ++j) {
        float sq = v[j] * v[j];
        asm("" : "+v"(sq));
        r[j] = sq;
    }
    #pragma unroll
    for (int m = 1; m < 8; ++m) {
        #pragma unroll
        for (int j = 0; j < 8; ++j) {
            float sq = v[8 * m + j] * v[8 * m + j];
            asm("" : "+v"(sq));
            r[j] += sq;
        }
    }
    s_w[k] = ((r[0] + r[1]) + (r[2] + r[3])) + ((r[4] + r[5]) + (r[6] + r[7]));
}

// ---- prep: transpose codebook so B-tile loads are coalesced ----
__global__ __launch_bounds__(64) void vq_transpose_kernel(
    const float* __restrict__ emb, float* __restrict__ WT)
{
    int k = blockIdx.x, t = threadIdx.x;
    WT[t * KCODES + k] = emb[k * DIMV + t];
}

// ---- main: tiled GEMM-style distance + argmin (no epilogue; 512 threads) ----
__global__ __launch_bounds__(512, 4) void vq_assign_kernel(
    const float* __restrict__ inp, const float* __restrict__ WT,
    const float* __restrict__ s_w, float* __restrict__ enc_out)
{
    __shared__ __align__(16) float At[64][128];   // g = 2f, [channel i][row r]
    __shared__ __align__(16) float Bt[64][128];   // codebook tile, [i][kk]
    __shared__ float sfL[128];

    const int t  = threadIdx.x;
    const int tx = t & 15;          // 16 k-columns of 8
    const int ty = t >> 4;          // 32 row-groups of 4
    const int n0 = blockIdx.x * 128;
    const int bq  = n0 >> 12;       // batch (stripe never crosses batch: 128 | 4096)
    const int hw0 = n0 & 4095;
    const float* fin = inp + (size_t)bq * (DIMV * HWSZ) + hw0;

    // ---- stage A: g = 2f into At[i][r], coalesced float4 loads ----
    // 64*128 floats = 2048 float4 / 512 threads = 4 iterations (r4 bug: was 16)
    #pragma unroll
    for (int j = 0; j < 4; ++j) {
        int id = j * 512 + t;       // [0, 2048)
        int i = id >> 5;            // 32 float4 per channel-row -> i in [0,64)
        int c4 = id & 31;
        float4 v = *(const float4*)(fin + (size_t)i * HWSZ + 4 * c4);
        float4 g4 = make_float4(v.x + v.x, v.y + v.y, v.z + v.z, v.w + v.w);
        *(float4*)&At[i][4 * c4] = g4;
    }
    __syncthreads();

    // ---- sf per row: numpy scalar-pairwise on f = 0.5*g (verbatim) ----
    if (t < 128) {
        float r8[8];
        #pragma unroll
        for (int j = 0; j < 8; ++j) {
            float h = 0.5f * At[j][t];
            float sq = h * h;
            asm("" : "+v"(sq));
            r8[j] = sq;
        }
        #pragma unroll
        for (int m = 1; m < 8; ++m) {
            #pragma unroll
            for (int j = 0; j < 8; ++j) {
                float h = 0.5f * At[8 * m + j][t];
                float sq = h * h;
                asm("" : "+v"(sq));
                r8[j] += sq;
            }
        }
        sfL[t] = ((r8[0] + r8[1]) + (r8[2] + r8[3])) + ((r8[4] + r8[5]) + (r8[6] + r8[7]));
    }
    __syncthreads();

    float sfr[4];
    #pragma unroll
    for (int r = 0; r < 4; ++r) sfr[r] = sfL[4 * ty + r];

    float bestv[4]; int bestk[4];
    #pragma unroll
    for (int r = 0; r < 4; ++r) { bestv[r] = 3.0e38f; bestk[r] = 0; }

    const float4* WT4 = (const float4*)WT;   // [64][256] in float4 units

    for (int kt = 0; kt < 8; ++kt) {
        __syncthreads();   // previous tile's Bt reads done
        #pragma unroll
        for (int c = 0; c < 4; ++c) {
            int idx4 = c * 512 + t;         // [0, 2048)
            int i = idx4 >> 5, kk4 = idx4 & 31;
            float4 v = WT4[i * 256 + kt * 32 + kk4];
            *(float4*)&Bt[i][kk4 * 4] = v;
        }
        __syncthreads();

        float acc[4][8];
        #pragma unroll
        for (int r = 0; r < 4; ++r)
            #pragma unroll
            for (int c = 0; c < 8; ++c) acc[r][c] = 0.0f;

        #pragma unroll 4
        for (int i = 0; i < 64; ++i) {
            float4 a0 = *(const float4*)&At[i][4 * ty];
            float4 b0 = *(const float4*)&Bt[i][4 * tx];
            float4 b1 = *(const float4*)&Bt[i][64 + 4 * tx];
            float av[4] = {a0.x, a0.y, a0.z, a0.w};
            float bv[8] = {b0.x, b0.y, b0.z, b0.w, b1.x, b1.y, b1.z, b1.w};
            #pragma unroll
            for (int r = 0; r < 4; ++r)
                #pragma unroll
                for (int c = 0; c < 8; ++c)
                    acc[r][c] = __builtin_fmaf(av[r], bv[c], acc[r][c]);
        }

        float4 sw0 = *(const float4*)&s_w[kt * 128 + 4 * tx];
        float4 sw1 = *(const float4*)&s_w[kt * 128 + 64 + 4 * tx];
        float swv[8] = {sw0.x, sw0.y, sw0.z, sw0.w, sw1.x, sw1.y, sw1.z, sw1.w};
        int kb0 = kt * 128 + 4 * tx;
        int kb1 = kt * 128 + 64 + 4 * tx;
        #pragma unroll
        for (int c = 0; c < 8; ++c) {        // ascending k within thread
            int kg = (c < 4) ? (kb0 + c) : (kb1 + (c - 4));
            #pragma unroll
            for (int r = 0; r < 4; ++r) {
                float d = (sfr[r] - acc[r][c]) + swv[c];
                if (d < bestv[r]) { bestv[r] = d; bestk[r] = kg; }
            }
        }
    }

    // ---- cross-thread argmin reduction (overlay on Bt) ----
    __syncthreads();
    float* bvv = &Bt[0][0];          // [128][16] floats (8 KB)
    int*   bii = (int*)&Bt[16][0];   // [128][16] ints   (8 KB)
    #pragma unroll
    for (int r = 0; r < 4; ++r) {
        bvv[(4 * ty + r) * 16 + tx] = bestv[r];
        bii[(4 * ty + r) * 16 + tx] = bestk[r];
    }
    __syncthreads();

    if (t < 128) {
        int r = t;
        float bv = bvv[r * 16];
        int   bk = bii[r * 16];
        #pragma unroll
        for (int x = 1; x < 16; ++x) {
            float v = bvv[r * 16 + x];
            int   k = bii[r * 16 + x];
            if (v < bv || (v == bv && k < bk)) { bv = v; bk = k; }
        }
        enc_out[n0 + r] = (float)bk;
    }
}

// ---- epilogue: q_out, counts, dw, loss (reads enc_out) ----
__global__ __launch_bounds__(256) void vq_epilogue_kernel(
    const float* __restrict__ inp, const float* __restrict__ emb,
    const float* __restrict__ enc_out,
    float* __restrict__ q_out, double* __restrict__ loss_sum,
    int* __restrict__ counts, float* __restrict__ dw)
{
    int n  = blockIdx.x * 256 + threadIdx.x;
    int b  = n >> 12;
    int hw = n & 4095;

    int bk = (int)enc_out[n];
    atomicAdd(&counts[bk], 1);

    const float* fin  = inp + (size_t)b * (DIMV * HWSZ) + hw;
    const float* wrow = emb + bk * DIMV;
    float* qo = q_out + (size_t)b * (DIMV * HWSZ) + hw;

    double l = 0.0;
    #pragma unroll
    for (int i = 0; i < DIMV; ++i) {
        float fi = fin[(size_t)i * HWSZ];   // coalesced
        float q  = wrow[i];                 // gather, L2-hot
        qo[(size_t)i * HWSZ] = q;           // coalesced
        double dq = (double)q - (double)fi;
        l = fma(dq, dq, l);
        atomicAdd(&dw[bk * DIMV + i], fi);
    }

    __shared__ double sm[256];
    sm[threadIdx.x] = l;
    __syncthreads();
    #pragma unroll
    for (int off = 128; off > 0; off >>= 1) {
        if (threadIdx.x < off) sm[threadIdx.x] += sm[threadIdx.x + off];
        __syncthreads();
    }
    if (threadIdx.x == 0) atomicAdd(loss_sum, sm[0]);
}

// ---- finalize A: cluster sizes, normalization, loss ----
__global__ __launch_bounds__(1024) void vq_finalizeA_kernel(
    const float* __restrict__ ema_cs, const int* __restrict__ counts,
    const double* __restrict__ loss_sum,
    float* __restrict__ out_loss, float* __restrict__ out_nll,
    float* __restrict__ out_ncs, double* __restrict__ adjd)
{
    int k = threadIdx.x;
    const double DECAY = 0.99;
    const double OMD   = 1.0 - 0.99;
    const double EPSV  = 1e-5;

    double ncs = (double)ema_cs[k] * DECAY + OMD * (double)counts[k];

    __shared__ double sm[1024];
    sm[k] = ncs;
    __syncthreads();
    #pragma unroll
    for (int off = 512; off > 0; off >>= 1) {
        if (k < off) sm[k] += sm[k + off];
        __syncthreads();
    }
    double nsum = sm[0];
    double adj = (ncs + EPSV) / (nsum + (double)KCODES * EPSV) * nsum;
    out_ncs[k] = (float)adj;
    adjd[k] = adj;

    if (k == 0) {
        double e = loss_sum[0] / (double)NELEM;
        out_loss[0] = (float)(e + 0.25 * e);
        out_nll[0]  = 1.0f;
    }
}

// ---- finalize B: EMA weights + normalized embedding ----
__global__ __launch_bounds__(256) void vq_finalizeB_kernel(
    const float* __restrict__ ema_w, const float* __restrict__ dw,
    const double* __restrict__ adjd,
    float* __restrict__ out_nema, float* __restrict__ out_nemb)
{
    int idx = blockIdx.x * 256 + threadIdx.x;   // 65536 total
    int k = idx >> 6;
    const double DECAY = 0.99;
    const double OMD   = 1.0 - 0.99;
    double ne = (double)ema_w[idx] * DECAY + OMD * (double)dw[idx];
    out_nema[idx] = (float)ne;
    out_nemb[idx] = (float)(ne / adjd[k]);
}

extern "C" void kernel_launch(void* const* d_in, const int* in_sizes, int n_in,
                              void* d_out, int out_size, void* d_ws, size_t ws_size,
                              hipStream_t stream) {
    const float* inp    = (const float*)d_in[0];  // (32,64,64,64) NCHW
    const float* emb    = (const float*)d_in[1];  // (1024,64)
    const float* ema_cs = (const float*)d_in[2];  // (1024,)
    const float* ema_w  = (const float*)d_in[3];  // (1024,64)

    char* ws = (char*)d_ws;
    double* loss_sum = (double*)(ws + 0);
    int*    counts   = (int*)   (ws + 8);
    float*  dw       = (float*) (ws + 4104);
    float*  s_w      = (float*) (ws + 266248);
    float*  WT       = (float*) (ws + 270344);
    double* adjd     = (double*)(ws + 532488);

    float* out       = (float*)d_out;
    float* q_out     = out;                       // 8388608
    float* enc_out   = out + 8388608;             // 131072
    float* out_loss  = out + 8519680;             // 1
    float* out_nll   = out + 8519681;             // 1
    float* out_ncs   = out + 8519682;             // 1024
    float* out_nema  = out + 8520706;             // 65536
    float* out_nemb  = out + 8586242;             // 65536

    hipMemsetAsync(ws, 0, 266248, stream);
    hipLaunchKernelGGL(vq_prep_kernel, dim3(4), dim3(256), 0, stream, emb, s_w);
    hipLaunchKernelGGL(vq_transpose_kernel, dim3(KCODES), dim3(64), 0, stream, emb, WT);
    hipLaunchKernelGGL(vq_assign_kernel, dim3(NROWS / 128), dim3(512), 0, stream,
                       inp, WT, s_w, enc_out);
    hipLaunchKernelGGL(vq_epilogue_kernel, dim3(NROWS / 256), dim3(256), 0, stream,
                       inp, emb, enc_out, q_out, loss_sum, counts, dw);
    hipLaunchKernelGGL(vq_finalizeA_kernel, dim3(1), dim3(1024), 0, stream,
                       ema_cs, counts, loss_sum, out_loss, out_nll, out_ncs, adjd);
    hipLaunchKernelGGL(vq_finalizeB_kernel, dim3(256), dim3(256), 0, stream,
                       ema_w, dw, adjd, out_nema, out_nemb);
}

// Round 6
// 515.713 us; speedup vs baseline: 1.8448x; 1.8448x over previous
//
#include <hip/hip_runtime.h>
#include <math.h>

// Problem constants
#define KCODES 1024
#define DIMV   64
#define NROWS  131072   // 32*64*64
#define HWSZ   4096     // 64*64
#define NELEM  8388608  // 32*64*64*64

// ws layout (bytes), 16B-aligned sections:
//   0       : double loss_sum            (8)
//   8       : int    counts[1024]        (4096)
//   4104    : int    cursor[1024]        (4096)
//   8200    : int    offs[1024]          (4096)
//   12304   : float  dw[65536]           (262144)
//   274448  : float  s_w[1024]           (4096)
//   278544  : float  WT[64*1024]         (262144)
//   540688  : double adjd[1024]          (8192)
//   548880  : int    rowlist[131072]     (524288)
// total 1073168; zeroed region = first 4104 bytes (loss_sum + counts)

// ---- prep: s_w in numpy scalar-pairwise order (identical to passing r2-r5) ----
__global__ __launch_bounds__(256) void vq_prep_kernel(
    const float* __restrict__ emb, float* __restrict__ s_w)
{
    int k = blockIdx.x * 256 + threadIdx.x;
    const float* v = emb + k * DIMV;
    float r[8];
    #pragma unroll
    for (int j = 0; j < 8; ++j) {
        float sq = v[j] * v[j];
        asm("" : "+v"(sq));
        r[j] = sq;
    }
    #pragma unroll
    for (int m = 1; m < 8; ++m) {
        #pragma unroll
        for (int j = 0; j < 8; ++j) {
            float sq = v[8 * m + j] * v[8 * m + j];
            asm("" : "+v"(sq));
            r[j] += sq;
        }
    }
    s_w[k] = ((r[0] + r[1]) + (r[2] + r[3])) + ((r[4] + r[5]) + (r[6] + r[7]));
}

// ---- prep: transpose codebook so B-tile loads are coalesced ----
__global__ __launch_bounds__(64) void vq_transpose_kernel(
    const float* __restrict__ emb, float* __restrict__ WT)
{
    int k = blockIdx.x, t = threadIdx.x;
    WT[t * KCODES + k] = emb[k * DIMV + t];
}

// ---- main: tiled GEMM-style distance + argmin (verbatim r5, which passed) ----
__global__ __launch_bounds__(512, 4) void vq_assign_kernel(
    const float* __restrict__ inp, const float* __restrict__ WT,
    const float* __restrict__ s_w, float* __restrict__ enc_out)
{
    __shared__ __align__(16) float At[64][128];
    __shared__ __align__(16) float Bt[64][128];
    __shared__ float sfL[128];

    const int t  = threadIdx.x;
    const int tx = t & 15;
    const int ty = t >> 4;
    const int n0 = blockIdx.x * 128;
    const int bq  = n0 >> 12;
    const int hw0 = n0 & 4095;
    const float* fin = inp + (size_t)bq * (DIMV * HWSZ) + hw0;

    #pragma unroll
    for (int j = 0; j < 4; ++j) {
        int id = j * 512 + t;
        int i = id >> 5;
        int c4 = id & 31;
        float4 v = *(const float4*)(fin + (size_t)i * HWSZ + 4 * c4);
        float4 g4 = make_float4(v.x + v.x, v.y + v.y, v.z + v.z, v.w + v.w);
        *(float4*)&At[i][4 * c4] = g4;
    }
    __syncthreads();

    if (t < 128) {
        float r8[8];
        #pragma unroll
        for (int j = 0; j < 8; ++j) {
            float h = 0.5f * At[j][t];
            float sq = h * h;
            asm("" : "+v"(sq));
            r8[j] = sq;
        }
        #pragma unroll
        for (int m = 1; m < 8; ++m) {
            #pragma unroll
            for (int j = 0; j < 8; ++j) {
                float h = 0.5f * At[8 * m + j][t];
                float sq = h * h;
                asm("" : "+v"(sq));
                r8[j] += sq;
            }
        }
        sfL[t] = ((r8[0] + r8[1]) + (r8[2] + r8[3])) + ((r8[4] + r8[5]) + (r8[6] + r8[7]));
    }
    __syncthreads();

    float sfr[4];
    #pragma unroll
    for (int r = 0; r < 4; ++r) sfr[r] = sfL[4 * ty + r];

    float bestv[4]; int bestk[4];
    #pragma unroll
    for (int r = 0; r < 4; ++r) { bestv[r] = 3.0e38f; bestk[r] = 0; }

    const float4* WT4 = (const float4*)WT;

    for (int kt = 0; kt < 8; ++kt) {
        __syncthreads();
        #pragma unroll
        for (int c = 0; c < 4; ++c) {
            int idx4 = c * 512 + t;
            int i = idx4 >> 5, kk4 = idx4 & 31;
            float4 v = WT4[i * 256 + kt * 32 + kk4];
            *(float4*)&Bt[i][kk4 * 4] = v;
        }
        __syncthreads();

        float acc[4][8];
        #pragma unroll
        for (int r = 0; r < 4; ++r)
            #pragma unroll
            for (int c = 0; c < 8; ++c) acc[r][c] = 0.0f;

        #pragma unroll 4
        for (int i = 0; i < 64; ++i) {
            float4 a0 = *(const float4*)&At[i][4 * ty];
            float4 b0 = *(const float4*)&Bt[i][4 * tx];
            float4 b1 = *(const float4*)&Bt[i][64 + 4 * tx];
            float av[4] = {a0.x, a0.y, a0.z, a0.w};
            float bv[8] = {b0.x, b0.y, b0.z, b0.w, b1.x, b1.y, b1.z, b1.w};
            #pragma unroll
            for (int r = 0; r < 4; ++r)
                #pragma unroll
                for (int c = 0; c < 8; ++c)
                    acc[r][c] = __builtin_fmaf(av[r], bv[c], acc[r][c]);
        }

        float4 sw0 = *(const float4*)&s_w[kt * 128 + 4 * tx];
        float4 sw1 = *(const float4*)&s_w[kt * 128 + 64 + 4 * tx];
        float swv[8] = {sw0.x, sw0.y, sw0.z, sw0.w, sw1.x, sw1.y, sw1.z, sw1.w};
        int kb0 = kt * 128 + 4 * tx;
        int kb1 = kt * 128 + 64 + 4 * tx;
        #pragma unroll
        for (int c = 0; c < 8; ++c) {
            int kg = (c < 4) ? (kb0 + c) : (kb1 + (c - 4));
            #pragma unroll
            for (int r = 0; r < 4; ++r) {
                float d = (sfr[r] - acc[r][c]) + swv[c];
                if (d < bestv[r]) { bestv[r] = d; bestk[r] = kg; }
            }
        }
    }

    __syncthreads();
    float* bvv = &Bt[0][0];
    int*   bii = (int*)&Bt[16][0];
    #pragma unroll
    for (int r = 0; r < 4; ++r) {
        bvv[(4 * ty + r) * 16 + tx] = bestv[r];
        bii[(4 * ty + r) * 16 + tx] = bestk[r];
    }
    __syncthreads();

    if (t < 128) {
        int r = t;
        float bv = bvv[r * 16];
        int   bk = bii[r * 16];
        #pragma unroll
        for (int x = 1; x < 16; ++x) {
            float v = bvv[r * 16 + x];
            int   k = bii[r * 16 + x];
            if (v < bv || (v == bv && k < bk)) { bv = v; bk = k; }
        }
        enc_out[n0 + r] = (float)bk;
    }
}

// ---- epilogue 1: counts (int atomics), q_out, loss. NO dw atomics. ----
__global__ __launch_bounds__(256) void vq_count_kernel(
    const float* __restrict__ inp, const float* __restrict__ emb,
    const float* __restrict__ enc_out,
    float* __restrict__ q_out, double* __restrict__ loss_sum,
    int* __restrict__ counts)
{
    int n  = blockIdx.x * 256 + threadIdx.x;
    int b  = n >> 12;
    int hw = n & 4095;

    int bk = (int)enc_out[n];
    atomicAdd(&counts[bk], 1);

    const float* fin  = inp + (size_t)b * (DIMV * HWSZ) + hw;
    const float* wrow = emb + bk * DIMV;
    float* qo = q_out + (size_t)b * (DIMV * HWSZ) + hw;

    double l = 0.0;
    #pragma unroll
    for (int i = 0; i < DIMV; ++i) {
        float fi = fin[(size_t)i * HWSZ];
        float q  = wrow[i];
        qo[(size_t)i * HWSZ] = q;
        double dq = (double)q - (double)fi;
        l = fma(dq, dq, l);
    }

    __shared__ double sm[256];
    sm[threadIdx.x] = l;
    __syncthreads();
    #pragma unroll
    for (int off = 128; off > 0; off >>= 1) {
        if (threadIdx.x < off) sm[threadIdx.x] += sm[threadIdx.x + off];
        __syncthreads();
    }
    if (threadIdx.x == 0) atomicAdd(loss_sum, sm[0]);
}

// ---- epilogue 2: finalizeA (ncs/adj/loss) + exclusive scan of counts ----
__global__ __launch_bounds__(1024) void vq_scan_finA_kernel(
    const float* __restrict__ ema_cs, const int* __restrict__ counts,
    const double* __restrict__ loss_sum,
    float* __restrict__ out_loss, float* __restrict__ out_nll,
    float* __restrict__ out_ncs, double* __restrict__ adjd,
    int* __restrict__ offs, int* __restrict__ cursor)
{
    int k = threadIdx.x;
    const double DECAY = 0.99;
    const double OMD   = 1.0 - 0.99;
    const double EPSV  = 1e-5;

    int cnt = counts[k];
    double ncs = (double)ema_cs[k] * DECAY + OMD * (double)cnt;

    __shared__ double sm[1024];
    sm[k] = ncs;
    __syncthreads();
    #pragma unroll
    for (int off = 512; off > 0; off >>= 1) {
        if (k < off) sm[k] += sm[k + off];
        __syncthreads();
    }
    double nsum = sm[0];
    __syncthreads();
    double adj = (ncs + EPSV) / (nsum + (double)KCODES * EPSV) * nsum;
    out_ncs[k] = (float)adj;
    adjd[k] = adj;

    // exclusive prefix sum of counts (Hillis-Steele inclusive, then - cnt)
    __shared__ int sc[1024];
    sc[k] = cnt;
    __syncthreads();
    #pragma unroll
    for (int off = 1; off < 1024; off <<= 1) {
        int v = (k >= off) ? sc[k - off] : 0;
        __syncthreads();
        sc[k] += v;
        __syncthreads();
    }
    int excl = sc[k] - cnt;
    offs[k] = excl;
    cursor[k] = excl;

    if (k == 0) {
        double e = loss_sum[0] / (double)NELEM;
        out_loss[0] = (float)(e + 0.25 * e);
        out_nll[0]  = 1.0f;
    }
}

// ---- epilogue 3: scatter row ids into per-code buckets ----
__global__ __launch_bounds__(256) void vq_place_kernel(
    const float* __restrict__ enc_out, int* __restrict__ cursor,
    int* __restrict__ rowlist)
{
    int n = blockIdx.x * 256 + threadIdx.x;
    int bk = (int)enc_out[n];
    int pos = atomicAdd(&cursor[bk], 1);
    rowlist[pos] = n;
}

// ---- epilogue 4: per-code segmented sum -> dw (plain stores) ----
__global__ __launch_bounds__(256) void vq_dw_kernel(
    const float* __restrict__ inp, const int* __restrict__ rowlist,
    const int* __restrict__ offs, const int* __restrict__ counts,
    float* __restrict__ dw)
{
    int k = blockIdx.x;
    int t = threadIdx.x;
    int i = t & 63;          // channel
    int sub = t >> 6;        // 0..3 row-slice
    int start = offs[k];
    int cnt = counts[k];

    float acc = 0.0f;
    #pragma unroll 4
    for (int r = sub; r < cnt; r += 4) {
        int n = rowlist[start + r];    // wave-uniform -> broadcast
        int b = n >> 12;
        int hw = n & 4095;
        acc += inp[(size_t)b * (DIMV * HWSZ) + (size_t)i * HWSZ + hw];
    }

    __shared__ float red[256];
    red[t] = acc;
    __syncthreads();
    if (t < 128) red[t] += red[t + 128];
    __syncthreads();
    if (t < 64) dw[k * DIMV + i] = red[t] + red[t + 64];
}

// ---- finalize B: EMA weights + normalized embedding ----
__global__ __launch_bounds__(256) void vq_finalizeB_kernel(
    const float* __restrict__ ema_w, const float* __restrict__ dw,
    const double* __restrict__ adjd,
    float* __restrict__ out_nema, float* __restrict__ out_nemb)
{
    int idx = blockIdx.x * 256 + threadIdx.x;
    int k = idx >> 6;
    const double DECAY = 0.99;
    const double OMD   = 1.0 - 0.99;
    double ne = (double)ema_w[idx] * DECAY + OMD * (double)dw[idx];
    out_nema[idx] = (float)ne;
    out_nemb[idx] = (float)(ne / adjd[k]);
}

extern "C" void kernel_launch(void* const* d_in, const int* in_sizes, int n_in,
                              void* d_out, int out_size, void* d_ws, size_t ws_size,
                              hipStream_t stream) {
    const float* inp    = (const float*)d_in[0];
    const float* emb    = (const float*)d_in[1];
    const float* ema_cs = (const float*)d_in[2];
    const float* ema_w  = (const float*)d_in[3];

    char* ws = (char*)d_ws;
    double* loss_sum = (double*)(ws + 0);
    int*    counts   = (int*)   (ws + 8);
    int*    cursor   = (int*)   (ws + 4104);
    int*    offs     = (int*)   (ws + 8200);
    float*  dw       = (float*) (ws + 12304);
    float*  s_w      = (float*) (ws + 274448);
    float*  WT       = (float*) (ws + 278544);
    double* adjd     = (double*)(ws + 540688);
    int*    rowlist  = (int*)   (ws + 548880);

    float* out       = (float*)d_out;
    float* q_out     = out;                       // 8388608
    float* enc_out   = out + 8388608;             // 131072
    float* out_loss  = out + 8519680;             // 1
    float* out_nll   = out + 8519681;             // 1
    float* out_ncs   = out + 8519682;             // 1024
    float* out_nema  = out + 8520706;             // 65536
    float* out_nemb  = out + 8586242;             // 65536

    hipMemsetAsync(ws, 0, 4104, stream);   // loss_sum + counts
    hipLaunchKernelGGL(vq_prep_kernel, dim3(4), dim3(256), 0, stream, emb, s_w);
    hipLaunchKernelGGL(vq_transpose_kernel, dim3(KCODES), dim3(64), 0, stream, emb, WT);
    hipLaunchKernelGGL(vq_assign_kernel, dim3(NROWS / 128), dim3(512), 0, stream,
                       inp, WT, s_w, enc_out);
    hipLaunchKernelGGL(vq_count_kernel, dim3(NROWS / 256), dim3(256), 0, stream,
                       inp, emb, enc_out, q_out, loss_sum, counts);
    hipLaunchKernelGGL(vq_scan_finA_kernel, dim3(1), dim3(1024), 0, stream,
                       ema_cs, counts, loss_sum, out_loss, out_nll, out_ncs,
                       adjd, offs, cursor);
    hipLaunchKernelGGL(vq_place_kernel, dim3(NROWS / 256), dim3(256), 0, stream,
                       enc_out, cursor, rowlist);
    hipLaunchKernelGGL(vq_dw_kernel, dim3(KCODES), dim3(256), 0, stream,
                       inp, rowlist, offs, counts, dw);
    hipLaunchKernelGGL(vq_finalizeB_kernel, dim3(256), dim3(256), 0, stream,
                       ema_w, dw, adjd, out_nema, out_nemb);
}

// Round 7
// 485.851 us; speedup vs baseline: 1.9582x; 1.0615x over previous
//
#include <hip/hip_runtime.h>
#include <math.h>

// Problem constants
#define KCODES 1024
#define DIMV   64
#define NROWS  131072   // 32*64*64
#define HWSZ   4096     // 64*64
#define NELEM  8388608  // 32*64*64*64

// ws layout (bytes):
//   0       : double loss_sum            (8)
//   8       : int    counts[1024]        (4096)
//   4104    : int    cursor[1024]        (4096)
//   8200    : int    offs[1024]          (4096)
//   12304   : (unused, was dw)           (262144)
//   274448  : float  s_w[1024]           (4096)
//   278544  : float  WT[64*1024]         (262144)
//   540688  : double adjd[1024]          (8192)
//   548880  : int    rowlist[131072]     (524288)
// zeroed region = first 4104 bytes (loss_sum + counts)

// ---- prep (fused): transpose codebook + s_w in numpy scalar-pairwise order ----
__global__ __launch_bounds__(64) void vq_prep2_kernel(
    const float* __restrict__ emb, float* __restrict__ s_w,
    float* __restrict__ WT)
{
    int k = blockIdx.x, t = threadIdx.x;
    float v = emb[k * DIMV + t];
    WT[t * KCODES + k] = v;

    __shared__ float sv[64];
    __shared__ float sr[8];
    sv[t] = v;
    __syncthreads();
    if (t < 8) {
        float x = sv[t];
        float sq = x * x;
        asm("" : "+v"(sq));
        float r = sq;
        #pragma unroll
        for (int m = 1; m < 8; ++m) {
            float y = sv[8 * m + t];
            float s2 = y * y;
            asm("" : "+v"(s2));
            r += s2;
        }
        sr[t] = r;
    }
    __syncthreads();
    if (t == 0)
        s_w[k] = ((sr[0] + sr[1]) + (sr[2] + sr[3])) + ((sr[4] + sr[5]) + (sr[6] + sr[7]));
}

// ---- main: 128x128 tile, 256 threads, 8x8 per thread (1.0 B/lane/FMA LDS) ----
__global__ __launch_bounds__(256, 2) void vq_assign_kernel(
    const float* __restrict__ inp, const float* __restrict__ WT,
    const float* __restrict__ s_w, float* __restrict__ enc_out)
{
    __shared__ __align__(16) float At[64][128];   // g = 2f, [channel i][row r]
    __shared__ __align__(16) float Bt[64][128];   // codebook tile, [i][kk]
    __shared__ float sfL[128];

    const int t  = threadIdx.x;
    const int tx = t & 15;          // 16 k-columns of 8
    const int ty = t >> 4;          // 16 row-groups of 8
    const int n0 = blockIdx.x * 128;
    const int bq  = n0 >> 12;
    const int hw0 = n0 & 4095;
    const float* fin = inp + (size_t)bq * (DIMV * HWSZ) + hw0;

    // stage A: 64*128 floats = 2048 float4 / 256 threads = 8 iters
    #pragma unroll
    for (int j = 0; j < 8; ++j) {
        int id = j * 256 + t;
        int i = id >> 5;
        int c4 = id & 31;
        float4 v = *(const float4*)(fin + (size_t)i * HWSZ + 4 * c4);
        float4 g4 = make_float4(v.x + v.x, v.y + v.y, v.z + v.z, v.w + v.w);
        *(float4*)&At[i][4 * c4] = g4;
    }
    __syncthreads();

    // sf per row: numpy scalar-pairwise on f = 0.5*g (verbatim passing code)
    if (t < 128) {
        float r8[8];
        #pragma unroll
        for (int j = 0; j < 8; ++j) {
            float h = 0.5f * At[j][t];
            float sq = h * h;
            asm("" : "+v"(sq));
            r8[j] = sq;
        }
        #pragma unroll
        for (int m = 1; m < 8; ++m) {
            #pragma unroll
            for (int j = 0; j < 8; ++j) {
                float h = 0.5f * At[8 * m + j][t];
                float sq = h * h;
                asm("" : "+v"(sq));
                r8[j] += sq;
            }
        }
        sfL[t] = ((r8[0] + r8[1]) + (r8[2] + r8[3])) + ((r8[4] + r8[5]) + (r8[6] + r8[7]));
    }
    __syncthreads();

    int rows[8];
    #pragma unroll
    for (int j = 0; j < 4; ++j) { rows[j] = 4 * ty + j; rows[4 + j] = 64 + 4 * ty + j; }
    float sfr[8];
    #pragma unroll
    for (int j = 0; j < 8; ++j) sfr[j] = sfL[rows[j]];

    float bestv[8]; int bestk[8];
    #pragma unroll
    for (int j = 0; j < 8; ++j) { bestv[j] = 3.0e38f; bestk[j] = 0; }

    const float4* WT4 = (const float4*)WT;   // [64][256] float4

    for (int kt = 0; kt < 8; ++kt) {
        __syncthreads();
        #pragma unroll
        for (int c = 0; c < 8; ++c) {
            int idx4 = c * 256 + t;
            int i = idx4 >> 5, kk4 = idx4 & 31;
            float4 v = WT4[i * 256 + kt * 32 + kk4];
            *(float4*)&Bt[i][kk4 * 4] = v;
        }
        __syncthreads();

        float acc[8][8];
        #pragma unroll
        for (int r = 0; r < 8; ++r)
            #pragma unroll
            for (int c = 0; c < 8; ++c) acc[r][c] = 0.0f;

        #pragma unroll 4
        for (int i = 0; i < 64; ++i) {
            float4 a0 = *(const float4*)&At[i][4 * ty];
            float4 a1 = *(const float4*)&At[i][64 + 4 * ty];
            float4 b0 = *(const float4*)&Bt[i][4 * tx];
            float4 b1 = *(const float4*)&Bt[i][64 + 4 * tx];
            float av[8] = {a0.x, a0.y, a0.z, a0.w, a1.x, a1.y, a1.z, a1.w};
            float bv[8] = {b0.x, b0.y, b0.z, b0.w, b1.x, b1.y, b1.z, b1.w};
            #pragma unroll
            for (int r = 0; r < 8; ++r)
                #pragma unroll
                for (int c = 0; c < 8; ++c)
                    acc[r][c] = __builtin_fmaf(av[r], bv[c], acc[r][c]);
        }

        float4 sw0 = *(const float4*)&s_w[kt * 128 + 4 * tx];
        float4 sw1 = *(const float4*)&s_w[kt * 128 + 64 + 4 * tx];
        float swv[8] = {sw0.x, sw0.y, sw0.z, sw0.w, sw1.x, sw1.y, sw1.z, sw1.w};
        int kb0 = kt * 128 + 4 * tx;
        int kb1 = kt * 128 + 64 + 4 * tx;
        #pragma unroll
        for (int c = 0; c < 8; ++c) {        // ascending k within thread
            int kg = (c < 4) ? (kb0 + c) : (kb1 + (c - 4));
            #pragma unroll
            for (int r = 0; r < 8; ++r) {
                float d = (sfr[r] - acc[r][c]) + swv[c];
                if (d < bestv[r]) { bestv[r] = d; bestk[r] = kg; }
            }
        }
    }

    // cross-thread argmin reduction (overlay on Bt)
    __syncthreads();
    float* bvv = &Bt[0][0];          // [128][16] floats
    int*   bii = (int*)&Bt[16][0];   // [128][16] ints
    #pragma unroll
    for (int j = 0; j < 8; ++j) {
        bvv[rows[j] * 16 + tx] = bestv[j];
        bii[rows[j] * 16 + tx] = bestk[j];
    }
    __syncthreads();

    if (t < 128) {
        int r = t;
        float bv = bvv[r * 16];
        int   bk = bii[r * 16];
        #pragma unroll
        for (int x = 1; x < 16; ++x) {
            float v = bvv[r * 16 + x];
            int   k = bii[r * 16 + x];
            if (v < bv || (v == bv && k < bk)) { bv = v; bk = k; }
        }
        enc_out[n0 + r] = (float)bk;
    }
}

// ---- epilogue 1: counts (int atomics), q_out, loss ----
__global__ __launch_bounds__(256) void vq_count_kernel(
    const float* __restrict__ inp, const float* __restrict__ emb,
    const float* __restrict__ enc_out,
    float* __restrict__ q_out, double* __restrict__ loss_sum,
    int* __restrict__ counts)
{
    int n  = blockIdx.x * 256 + threadIdx.x;
    int b  = n >> 12;
    int hw = n & 4095;

    int bk = (int)enc_out[n];
    atomicAdd(&counts[bk], 1);

    const float* fin  = inp + (size_t)b * (DIMV * HWSZ) + hw;
    const float* wrow = emb + bk * DIMV;
    float* qo = q_out + (size_t)b * (DIMV * HWSZ) + hw;

    double l = 0.0;
    #pragma unroll
    for (int i = 0; i < DIMV; ++i) {
        float fi = fin[(size_t)i * HWSZ];
        float q  = wrow[i];
        qo[(size_t)i * HWSZ] = q;
        double dq = (double)q - (double)fi;
        l = fma(dq, dq, l);
    }

    __shared__ double sm[256];
    sm[threadIdx.x] = l;
    __syncthreads();
    #pragma unroll
    for (int off = 128; off > 0; off >>= 1) {
        if (threadIdx.x < off) sm[threadIdx.x] += sm[threadIdx.x + off];
        __syncthreads();
    }
    if (threadIdx.x == 0) atomicAdd(loss_sum, sm[0]);
}

// ---- epilogue 2: finalizeA (ncs/adj/loss) + exclusive scan of counts ----
__global__ __launch_bounds__(1024) void vq_scan_finA_kernel(
    const float* __restrict__ ema_cs, const int* __restrict__ counts,
    const double* __restrict__ loss_sum,
    float* __restrict__ out_loss, float* __restrict__ out_nll,
    float* __restrict__ out_ncs, double* __restrict__ adjd,
    int* __restrict__ offs, int* __restrict__ cursor)
{
    int k = threadIdx.x;
    const double DECAY = 0.99;
    const double OMD   = 1.0 - 0.99;
    const double EPSV  = 1e-5;

    int cnt = counts[k];
    double ncs = (double)ema_cs[k] * DECAY + OMD * (double)cnt;

    __shared__ double sm[1024];
    sm[k] = ncs;
    __syncthreads();
    #pragma unroll
    for (int off = 512; off > 0; off >>= 1) {
        if (k < off) sm[k] += sm[k + off];
        __syncthreads();
    }
    double nsum = sm[0];
    __syncthreads();
    double adj = (ncs + EPSV) / (nsum + (double)KCODES * EPSV) * nsum;
    out_ncs[k] = (float)adj;
    adjd[k] = adj;

    __shared__ int sc[1024];
    sc[k] = cnt;
    __syncthreads();
    #pragma unroll
    for (int off = 1; off < 1024; off <<= 1) {
        int v = (k >= off) ? sc[k - off] : 0;
        __syncthreads();
        sc[k] += v;
        __syncthreads();
    }
    int excl = sc[k] - cnt;
    offs[k] = excl;
    cursor[k] = excl;

    if (k == 0) {
        double e = loss_sum[0] / (double)NELEM;
        out_loss[0] = (float)(e + 0.25 * e);
        out_nll[0]  = 1.0f;
    }
}

// ---- epilogue 3: scatter row ids into per-code buckets ----
__global__ __launch_bounds__(256) void vq_place_kernel(
    const float* __restrict__ enc_out, int* __restrict__ cursor,
    int* __restrict__ rowlist)
{
    int n = blockIdx.x * 256 + threadIdx.x;
    int bk = (int)enc_out[n];
    int pos = atomicAdd(&cursor[bk], 1);
    rowlist[pos] = n;
}

// ---- epilogue 4 (fused finB): per-code sum -> dw -> nema/nemb ----
__global__ __launch_bounds__(256) void vq_dw_finB_kernel(
    const float* __restrict__ inp, const int* __restrict__ rowlist,
    const int* __restrict__ offs, const int* __restrict__ counts,
    const float* __restrict__ ema_w, const double* __restrict__ adjd,
    float* __restrict__ out_nema, float* __restrict__ out_nemb)
{
    int k = blockIdx.x;
    int t = threadIdx.x;
    int i = t & 63;          // channel
    int sub = t >> 6;        // 0..3 row-slice
    int start = offs[k];
    int cnt = counts[k];

    float acc = 0.0f;
    #pragma unroll 4
    for (int r = sub; r < cnt; r += 4) {
        int n = rowlist[start + r];    // wave-uniform -> broadcast
        int b = n >> 12;
        int hw = n & 4095;
        acc += inp[(size_t)b * (DIMV * HWSZ) + (size_t)i * HWSZ + hw];
    }

    __shared__ float red[256];
    red[t] = acc;
    __syncthreads();
    if (t < 128) red[t] += red[t + 128];
    __syncthreads();
    if (t < 64) {
        float dwv = red[t] + red[t + 64];
        const double DECAY = 0.99;
        const double OMD   = 1.0 - 0.99;
        int idx = k * DIMV + i;
        double ne = (double)ema_w[idx] * DECAY + OMD * (double)dwv;
        out_nema[idx] = (float)ne;
        out_nemb[idx] = (float)(ne / adjd[k]);
    }
}

extern "C" void kernel_launch(void* const* d_in, const int* in_sizes, int n_in,
                              void* d_out, int out_size, void* d_ws, size_t ws_size,
                              hipStream_t stream) {
    const float* inp    = (const float*)d_in[0];
    const float* emb    = (const float*)d_in[1];
    const float* ema_cs = (const float*)d_in[2];
    const float* ema_w  = (const float*)d_in[3];

    char* ws = (char*)d_ws;
    double* loss_sum = (double*)(ws + 0);
    int*    counts   = (int*)   (ws + 8);
    int*    cursor   = (int*)   (ws + 4104);
    int*    offs     = (int*)   (ws + 8200);
    float*  s_w      = (float*) (ws + 274448);
    float*  WT       = (float*) (ws + 278544);
    double* adjd     = (double*)(ws + 540688);
    int*    rowlist  = (int*)   (ws + 548880);

    float* out       = (float*)d_out;
    float* q_out     = out;                       // 8388608
    float* enc_out   = out + 8388608;             // 131072
    float* out_loss  = out + 8519680;             // 1
    float* out_nll   = out + 8519681;             // 1
    float* out_ncs   = out + 8519682;             // 1024
    float* out_nema  = out + 8520706;             // 65536
    float* out_nemb  = out + 8586242;             // 65536

    hipMemsetAsync(ws, 0, 4104, stream);   // loss_sum + counts
    hipLaunchKernelGGL(vq_prep2_kernel, dim3(KCODES), dim3(64), 0, stream,
                       emb, s_w, WT);
    hipLaunchKernelGGL(vq_assign_kernel, dim3(NROWS / 128), dim3(256), 0, stream,
                       inp, WT, s_w, enc_out);
    hipLaunchKernelGGL(vq_count_kernel, dim3(NROWS / 256), dim3(256), 0, stream,
                       inp, emb, enc_out, q_out, loss_sum, counts);
    hipLaunchKernelGGL(vq_scan_finA_kernel, dim3(1), dim3(1024), 0, stream,
                       ema_cs, counts, loss_sum, out_loss, out_nll, out_ncs,
                       adjd, offs, cursor);
    hipLaunchKernelGGL(vq_place_kernel, dim3(NROWS / 256), dim3(256), 0, stream,
                       enc_out, cursor, rowlist);
    hipLaunchKernelGGL(vq_dw_finB_kernel, dim3(KCODES), dim3(256), 0, stream,
                       inp, rowlist, offs, counts, ema_w, adjd,
                       out_nema, out_nemb);
}